// Round 1
// baseline (318.598 us; speedup 1.0000x reference)
//
#include <hip/hip_runtime.h>
#include <math.h>

// MaskedBalancedBCELoss — exact hard-negative-mining via 3-level radix select
// on float bit patterns (losses are strictly positive => uint bit order ==
// value order).
//
// ws layout:
//   [0, 256)              Ctrl struct (zeroed each call via hipMemsetAsync)
//   [256, 256+16384)      hist1: 4096 x uint  (level-1 histogram, counts only)
//   [16640, ...)          candidate buffer (boundary-bin float bits)

#define NBINS1 4096
#define NBINS2 4096
#define NBINS3 128
#define K1_BLOCKS 1024
#define K3_MAX_LOCAL 7168          // per-block LDS candidate staging (uints)
#define K3_VEC_PER_BLOCK 1792      // 7 iters * 256 threads (float4 units)

struct Ctrl {
  unsigned long long pos_cnt;
  unsigned long long neg_cnt;
  unsigned long long k;        // neg_count (selected)
  double pos_sum;
  double sum_above;            // sum of neg losses with bin1 > B
  int B;                       // level-1 boundary bin; NBINS1 => none (k==0)
  unsigned k_rem;              // remaining to take inside bin B
  unsigned cand_cnt;
};

__device__ __forceinline__ float neg_loss_from(float p) {
  // loss at a negative pixel: -max(log1p(-p), -100)
  return -fmaxf(log1pf(-p), -100.0f);
}
__device__ __forceinline__ float pos_loss_from(float p) {
  // loss at a positive pixel: -max(log(p), -100)
  return -fmaxf(logf(p), -100.0f);
}

// ---------------- Kernel 1: reductions + level-1 histogram -----------------
extern "C" __global__ void __launch_bounds__(256)
k1_hist(const float* __restrict__ pred, const float* __restrict__ gt,
        const float* __restrict__ mask, unsigned* __restrict__ hist1,
        Ctrl* __restrict__ ctrl, int n4, int n) {
  __shared__ unsigned h[NBINS1];
  for (int i = threadIdx.x; i < NBINS1; i += blockDim.x) h[i] = 0u;
  __syncthreads();

  unsigned pc = 0, nc = 0;
  double psum = 0.0;
  const float4* p4 = (const float4*)pred;
  const float4* g4 = (const float4*)gt;
  const float4* m4 = (const float4*)mask;
  int gtid = blockIdx.x * blockDim.x + threadIdx.x;
  int stride = gridDim.x * blockDim.x;

  for (int i = gtid; i < n4; i += stride) {
    float4 pv = p4[i], gv = g4[i], mv = m4[i];
    float pa[4] = {pv.x, pv.y, pv.z, pv.w};
    float ga[4] = {gv.x, gv.y, gv.z, gv.w};
    float ma[4] = {mv.x, mv.y, mv.z, mv.w};
#pragma unroll
    for (int j = 0; j < 4; j++) {
      if (ma[j] != 0.0f) {
        if (ga[j] != 0.0f) {
          pc++; psum += (double)pos_loss_from(pa[j]);
        } else {
          nc++;
          float loss = neg_loss_from(pa[j]);
          atomicAdd(&h[__float_as_uint(loss) >> 19], 1u);
        }
      }
    }
  }
  // scalar tail (n % 4 != 0)
  for (int i = n4 * 4 + gtid; i < n; i += stride) {
    float p = pred[i], g = gt[i], m = mask[i];
    if (m != 0.0f) {
      if (g != 0.0f) { pc++; psum += (double)pos_loss_from(p); }
      else {
        nc++;
        atomicAdd(&h[__float_as_uint(neg_loss_from(p)) >> 19], 1u);
      }
    }
  }

  // block reduce pc/nc/psum
  unsigned long long pcl = pc, ncl = nc;
  for (int off = 32; off > 0; off >>= 1) {
    pcl += __shfl_down(pcl, off);
    ncl += __shfl_down(ncl, off);
    psum += __shfl_down(psum, off);
  }
  __shared__ unsigned long long spc[4], snc[4];
  __shared__ double sps[4];
  int wv = threadIdx.x >> 6, ln = threadIdx.x & 63;
  if (ln == 0) { spc[wv] = pcl; snc[wv] = ncl; sps[wv] = psum; }
  __syncthreads();   // also ensures all LDS histogram atomics are complete
  if (threadIdx.x == 0) {
    unsigned long long tp = 0, tn = 0; double ts = 0.0;
    for (int w = 0; w < 4; w++) { tp += spc[w]; tn += snc[w]; ts += sps[w]; }
    atomicAdd(&ctrl->pos_cnt, tp);
    atomicAdd(&ctrl->neg_cnt, tn);
    atomicAdd(&ctrl->pos_sum, ts);
  }
  // flush LDS histogram to global (skip empty bins)
  for (int i = threadIdx.x; i < NBINS1; i += blockDim.x) {
    unsigned c = h[i];
    if (c) atomicAdd(&hist1[i], c);
  }
}

// ---------- Kernel 2: pick k, find level-1 boundary bin (1 block) ----------
extern "C" __global__ void __launch_bounds__(256)
k2_select(const unsigned* __restrict__ hist1, Ctrl* __restrict__ ctrl) {
  const int T = 256, CH = NBINS1 / T;  // 16 bins per thread
  __shared__ unsigned long long sarr[T];
  __shared__ unsigned long long sk;
  int t = threadIdx.x;

  unsigned cnt[CH];
  unsigned long long tot = 0;
  for (int j = 0; j < CH; j++) { cnt[j] = hist1[t * CH + j]; tot += cnt[j]; }
  sarr[t] = tot;
  __syncthreads();
  // inclusive suffix scan (Hillis-Steele): sarr[t] = sum_{u>=t} chunk[u]
  for (int off = 1; off < T; off <<= 1) {
    unsigned long long v = (t + off < T) ? sarr[t + off] : 0ull;
    __syncthreads();
    sarr[t] += v;
    __syncthreads();
  }
  if (t == 0) {
    unsigned long long pos = ctrl->pos_cnt, negtot = ctrl->neg_cnt;
    unsigned long long k = 0;
    if (pos > 0) {                 // FALLBACK_NEG=0 when pos==0
      k = pos * 3ull;              // floor(pos*3.0), exact in integer
      if (k > negtot) k = negtot;
    }
    ctrl->k = k;
    sk = k;
    if (k == 0) { ctrl->B = NBINS1; ctrl->k_rem = 0u; }
  }
  __syncthreads();
  unsigned long long k = sk;
  if (k > 0) {
    unsigned long long above = sarr[t] - tot;   // strictly-above-this-chunk
    if (above < k && sarr[t] >= k) {            // crossing inside my chunk
      unsigned long long cum = above;
      for (int j = CH - 1; j >= 0; j--) {
        if (cum + (unsigned long long)cnt[j] >= k) {
          ctrl->B = t * CH + j;
          ctrl->k_rem = (unsigned)(k - cum);
          break;
        }
        cum += cnt[j];
      }
    }
  }
}

// -------- Kernel 3: sum above bin B + compact boundary-bin candidates ------
extern "C" __global__ void __launch_bounds__(256)
k3_compact(const float* __restrict__ pred, const float* __restrict__ gt,
           const float* __restrict__ mask, Ctrl* __restrict__ ctrl,
           unsigned* __restrict__ cand, unsigned cap, int n4, int n) {
  __shared__ unsigned lbuf[K3_MAX_LOCAL];
  __shared__ unsigned lcnt;
  __shared__ unsigned gbase;
  __shared__ double sws[4];
  if (threadIdx.x == 0) { lcnt = 0u; gbase = 0u; }
  __syncthreads();

  const int B = ctrl->B;
  double ssum = 0.0;
  const float4* p4 = (const float4*)pred;
  const float4* g4 = (const float4*)gt;
  const float4* m4 = (const float4*)mask;
  int gtid = blockIdx.x * blockDim.x + threadIdx.x;
  int stride = gridDim.x * blockDim.x;

  for (int i = gtid; i < n4; i += stride) {
    float4 pv = p4[i], gv = g4[i], mv = m4[i];
    float pa[4] = {pv.x, pv.y, pv.z, pv.w};
    float ga[4] = {gv.x, gv.y, gv.z, gv.w};
    float ma[4] = {mv.x, mv.y, mv.z, mv.w};
#pragma unroll
    for (int j = 0; j < 4; j++) {
      if (ma[j] != 0.0f && ga[j] == 0.0f) {
        float loss = neg_loss_from(pa[j]);
        unsigned bits = __float_as_uint(loss);
        int b = (int)(bits >> 19);
        if (b > B) ssum += (double)loss;
        else if (b == B) {
          unsigned idx = atomicAdd(&lcnt, 1u);
          if (idx < K3_MAX_LOCAL) lbuf[idx] = bits;
        }
      }
    }
  }
  for (int i = n4 * 4 + gtid; i < n; i += stride) {
    float p = pred[i], g = gt[i], m = mask[i];
    if (m != 0.0f && g == 0.0f) {
      float loss = neg_loss_from(p);
      unsigned bits = __float_as_uint(loss);
      int b = (int)(bits >> 19);
      if (b > B) ssum += (double)loss;
      else if (b == B) {
        unsigned idx = atomicAdd(&lcnt, 1u);
        if (idx < K3_MAX_LOCAL) lbuf[idx] = bits;
      }
    }
  }

  for (int off = 32; off > 0; off >>= 1) ssum += __shfl_down(ssum, off);
  int wv = threadIdx.x >> 6, ln = threadIdx.x & 63;
  if (ln == 0) sws[wv] = ssum;
  __syncthreads();   // all appends + wave sums complete
  if (threadIdx.x == 0) {
    double tsum = sws[0] + sws[1] + sws[2] + sws[3];
    atomicAdd(&ctrl->sum_above, tsum);
    unsigned c = lcnt;
    if (c > K3_MAX_LOCAL) c = K3_MAX_LOCAL;
    lcnt = c;
    gbase = c ? atomicAdd(&ctrl->cand_cnt, c) : 0u;
  }
  __syncthreads();
  unsigned c = lcnt, base = gbase;
  for (unsigned i = threadIdx.x; i < c; i += blockDim.x) {
    unsigned dst = base + i;
    if (dst < cap) cand[dst] = lbuf[i];
  }
}

// ------- Kernel 4: levels 2+3 on candidates, final result (1 block) --------
extern "C" __global__ void __launch_bounds__(1024)
k4_final(const unsigned* __restrict__ cand, Ctrl* __restrict__ ctrl,
         float* __restrict__ out, unsigned cap) {
  const int T = 1024, CH2 = NBINS2 / T;  // 4 bins per thread
  __shared__ unsigned h2[NBINS2];
  __shared__ unsigned h3[NBINS3];
  __shared__ unsigned long long sarr[T];
  __shared__ int sB2;
  __shared__ unsigned sk2;
  __shared__ double sws[16];
  int t = threadIdx.x;

  unsigned M = ctrl->cand_cnt; if (M > cap) M = cap;
  unsigned k_rem = ctrl->k_rem;

  for (int i = t; i < NBINS2; i += T) h2[i] = 0u;
  for (int i = t; i < NBINS3; i += T) h3[i] = 0u;
  if (t == 0) { sB2 = NBINS2; sk2 = 0u; }
  __syncthreads();

  if (k_rem > 0) {
    for (unsigned i = t; i < M; i += T)
      atomicAdd(&h2[(cand[i] >> 7) & 0xFFFu], 1u);
  }
  __syncthreads();

  // suffix scan over 4-bin chunks of h2
  unsigned cnt2[CH2];
  unsigned long long tot = 0;
  for (int j = 0; j < CH2; j++) { cnt2[j] = h2[t * CH2 + j]; tot += cnt2[j]; }
  sarr[t] = tot;
  __syncthreads();
  for (int off = 1; off < T; off <<= 1) {
    unsigned long long v = (t + off < T) ? sarr[t + off] : 0ull;
    __syncthreads();
    sarr[t] += v;
    __syncthreads();
  }
  if (k_rem > 0) {
    unsigned long long above = sarr[t] - tot;
    if (above < (unsigned long long)k_rem &&
        sarr[t] >= (unsigned long long)k_rem) {
      unsigned long long cum = above;
      for (int j = CH2 - 1; j >= 0; j--) {
        if (cum + (unsigned long long)cnt2[j] >= (unsigned long long)k_rem) {
          sB2 = t * CH2 + j;
          sk2 = (unsigned)((unsigned long long)k_rem - cum);
          break;
        }
        cum += cnt2[j];
      }
    }
  }
  __syncthreads();
  int B2 = sB2; unsigned k2r = sk2;

  // sum values strictly above sub-bin B2; exact-value histogram inside B2
  double ssum = 0.0;
  if (k_rem > 0) {
    for (unsigned i = t; i < M; i += T) {
      unsigned bits = cand[i];
      int b2 = (int)((bits >> 7) & 0xFFFu);
      if (b2 > B2) ssum += (double)__uint_as_float(bits);
      else if (b2 == B2) atomicAdd(&h3[bits & 0x7Fu], 1u);
    }
  }
  for (int off = 32; off > 0; off >>= 1) ssum += __shfl_down(ssum, off);
  int wv = t >> 6, ln = t & 63;
  if (ln == 0) sws[wv] = ssum;
  __syncthreads();

  if (t == 0) {
    double sum2 = 0.0;
    for (int w = 0; w < T / 64; w++) sum2 += sws[w];
    double partial = 0.0;
    unsigned rem = k2r;
    unsigned base = ((unsigned)ctrl->B << 19) | ((unsigned)B2 << 7);
    for (int b = NBINS3 - 1; b >= 0 && rem > 0; b--) {
      unsigned c = h3[b];
      if (!c) continue;
      unsigned take = (c < rem) ? c : rem;
      // all 32 bits fixed here => ties share one exact value
      partial += (double)take * (double)__uint_as_float(base | (unsigned)b);
      rem -= take;
    }
    double neg_sum = ctrl->sum_above + sum2 + partial;
    double denom = (double)ctrl->pos_cnt + (double)ctrl->k + 1e-6;
    out[0] = (float)((ctrl->pos_sum + neg_sum) / denom);
  }
}

// ---------------------------------------------------------------------------
extern "C" void kernel_launch(void* const* d_in, const int* in_sizes, int n_in,
                              void* d_out, int out_size, void* d_ws, size_t ws_size,
                              hipStream_t stream) {
  const float* pred = (const float*)d_in[0];
  const float* gt   = (const float*)d_in[1];
  const float* mask = (const float*)d_in[2];
  float* out = (float*)d_out;
  int n = in_sizes[0];
  int n4 = n / 4;

  char* ws = (char*)d_ws;
  Ctrl* ctrl = (Ctrl*)ws;
  unsigned* hist1 = (unsigned*)(ws + 256);
  size_t cand_off = 256 + (size_t)NBINS1 * sizeof(unsigned);
  unsigned* cand = (unsigned*)(ws + cand_off);
  unsigned cap = 0;
  if (ws_size > cand_off + 4) {
    size_t c = (ws_size - cand_off) / 4;
    cap = (c > (size_t)n) ? (unsigned)n : (unsigned)c;
  }

  hipMemsetAsync(d_ws, 0, cand_off, stream);
  k1_hist<<<K1_BLOCKS, 256, 0, stream>>>(pred, gt, mask, hist1, ctrl, n4, n);
  k2_select<<<1, 256, 0, stream>>>(hist1, ctrl);
  int blocks3 = (n4 + K3_VEC_PER_BLOCK - 1) / K3_VEC_PER_BLOCK;
  if (blocks3 < 1) blocks3 = 1;
  k3_compact<<<blocks3, 256, 0, stream>>>(pred, gt, mask, ctrl, cand, cap, n4, n);
  k4_final<<<1, 1024, 0, stream>>>(cand, ctrl, out, cap);
}

// Round 2
// 312.349 us; speedup vs baseline: 1.0200x; 1.0200x over previous
//
#include <hip/hip_runtime.h>
#include <math.h>

// MaskedBalancedBCELoss — exact hard-negative-mining via 3-level radix select
// on float bit patterns (losses are strictly positive => uint bit order ==
// value order).
//
// R1 change: libm logf/log1pf -> hardware v_log_f32 (__log2f * ln2).
// Selection is done on OUR loss bits (consistent across k1/k3/k4), so
// select remains exact; value error ~1e-7 rel, far under threshold.
//
// ws layout:
//   [0, 256)              Ctrl struct (zeroed each call via hipMemsetAsync)
//   [256, 256+16384)      hist1: 4096 x uint  (level-1 histogram, counts only)
//   [16640, ...)          candidate buffer (boundary-bin float bits)

#define NBINS1 4096
#define NBINS2 4096
#define NBINS3 128
#define K1_BLOCKS 1024
#define K3_MAX_LOCAL 7168          // per-block LDS candidate staging (uints)
#define K3_VEC_PER_BLOCK 1792      // 7 iters * 256 threads (float4 units)

struct Ctrl {
  unsigned long long pos_cnt;
  unsigned long long neg_cnt;
  unsigned long long k;        // neg_count (selected)
  double pos_sum;
  double sum_above;            // sum of neg losses with bin1 > B
  int B;                       // level-1 boundary bin; NBINS1 => none (k==0)
  unsigned k_rem;              // remaining to take inside bin B
  unsigned cand_cnt;
};

#define LN2F 0.69314718055994530942f

__device__ __forceinline__ float neg_loss_from(float p) {
  // loss at a negative pixel: -max(log(1-p), -100). v_log_f32(0)=-inf, so the
  // clamp still catches p==1 exactly.
  return -fmaxf(__log2f(1.0f - p) * LN2F, -100.0f);
}
__device__ __forceinline__ float pos_loss_from(float p) {
  // loss at a positive pixel: -max(log(p), -100)
  return -fmaxf(__log2f(p) * LN2F, -100.0f);
}

// ---------------- Kernel 1: reductions + level-1 histogram -----------------
extern "C" __global__ void __launch_bounds__(256)
k1_hist(const float* __restrict__ pred, const float* __restrict__ gt,
        const float* __restrict__ mask, unsigned* __restrict__ hist1,
        Ctrl* __restrict__ ctrl, int n4, int n) {
  __shared__ unsigned h[NBINS1];
  for (int i = threadIdx.x; i < NBINS1; i += blockDim.x) h[i] = 0u;
  __syncthreads();

  unsigned pc = 0, nc = 0;
  double psum = 0.0;
  const float4* p4 = (const float4*)pred;
  const float4* g4 = (const float4*)gt;
  const float4* m4 = (const float4*)mask;
  int gtid = blockIdx.x * blockDim.x + threadIdx.x;
  int stride = gridDim.x * blockDim.x;

  for (int i = gtid; i < n4; i += stride) {
    float4 pv = p4[i], gv = g4[i], mv = m4[i];
    float pa[4] = {pv.x, pv.y, pv.z, pv.w};
    float ga[4] = {gv.x, gv.y, gv.z, gv.w};
    float ma[4] = {mv.x, mv.y, mv.z, mv.w};
#pragma unroll
    for (int j = 0; j < 4; j++) {
      if (ma[j] != 0.0f) {
        if (ga[j] != 0.0f) {
          pc++; psum += (double)pos_loss_from(pa[j]);
        } else {
          nc++;
          float loss = neg_loss_from(pa[j]);
          atomicAdd(&h[__float_as_uint(loss) >> 19], 1u);
        }
      }
    }
  }
  // scalar tail (n % 4 != 0)
  for (int i = n4 * 4 + gtid; i < n; i += stride) {
    float p = pred[i], g = gt[i], m = mask[i];
    if (m != 0.0f) {
      if (g != 0.0f) { pc++; psum += (double)pos_loss_from(p); }
      else {
        nc++;
        atomicAdd(&h[__float_as_uint(neg_loss_from(p)) >> 19], 1u);
      }
    }
  }

  // block reduce pc/nc/psum
  unsigned long long pcl = pc, ncl = nc;
  for (int off = 32; off > 0; off >>= 1) {
    pcl += __shfl_down(pcl, off);
    ncl += __shfl_down(ncl, off);
    psum += __shfl_down(psum, off);
  }
  __shared__ unsigned long long spc[4], snc[4];
  __shared__ double sps[4];
  int wv = threadIdx.x >> 6, ln = threadIdx.x & 63;
  if (ln == 0) { spc[wv] = pcl; snc[wv] = ncl; sps[wv] = psum; }
  __syncthreads();   // also ensures all LDS histogram atomics are complete
  if (threadIdx.x == 0) {
    unsigned long long tp = 0, tn = 0; double ts = 0.0;
    for (int w = 0; w < 4; w++) { tp += spc[w]; tn += snc[w]; ts += sps[w]; }
    atomicAdd(&ctrl->pos_cnt, tp);
    atomicAdd(&ctrl->neg_cnt, tn);
    atomicAdd(&ctrl->pos_sum, ts);
  }
  // flush LDS histogram to global (skip empty bins)
  for (int i = threadIdx.x; i < NBINS1; i += blockDim.x) {
    unsigned c = h[i];
    if (c) atomicAdd(&hist1[i], c);
  }
}

// ---------- Kernel 2: pick k, find level-1 boundary bin (1 block) ----------
extern "C" __global__ void __launch_bounds__(256)
k2_select(const unsigned* __restrict__ hist1, Ctrl* __restrict__ ctrl) {
  const int T = 256, CH = NBINS1 / T;  // 16 bins per thread
  __shared__ unsigned long long sarr[T];
  __shared__ unsigned long long sk;
  int t = threadIdx.x;

  unsigned cnt[CH];
  unsigned long long tot = 0;
  for (int j = 0; j < CH; j++) { cnt[j] = hist1[t * CH + j]; tot += cnt[j]; }
  sarr[t] = tot;
  __syncthreads();
  // inclusive suffix scan (Hillis-Steele): sarr[t] = sum_{u>=t} chunk[u]
  for (int off = 1; off < T; off <<= 1) {
    unsigned long long v = (t + off < T) ? sarr[t + off] : 0ull;
    __syncthreads();
    sarr[t] += v;
    __syncthreads();
  }
  if (t == 0) {
    unsigned long long pos = ctrl->pos_cnt, negtot = ctrl->neg_cnt;
    unsigned long long k = 0;
    if (pos > 0) {                 // FALLBACK_NEG=0 when pos==0
      k = pos * 3ull;              // floor(pos*3.0), exact in integer
      if (k > negtot) k = negtot;
    }
    ctrl->k = k;
    sk = k;
    if (k == 0) { ctrl->B = NBINS1; ctrl->k_rem = 0u; }
  }
  __syncthreads();
  unsigned long long k = sk;
  if (k > 0) {
    unsigned long long above = sarr[t] - tot;   // strictly-above-this-chunk
    if (above < k && sarr[t] >= k) {            // crossing inside my chunk
      unsigned long long cum = above;
      for (int j = CH - 1; j >= 0; j--) {
        if (cum + (unsigned long long)cnt[j] >= k) {
          ctrl->B = t * CH + j;
          ctrl->k_rem = (unsigned)(k - cum);
          break;
        }
        cum += cnt[j];
      }
    }
  }
}

// -------- Kernel 3: sum above bin B + compact boundary-bin candidates ------
extern "C" __global__ void __launch_bounds__(256)
k3_compact(const float* __restrict__ pred, const float* __restrict__ gt,
           const float* __restrict__ mask, Ctrl* __restrict__ ctrl,
           unsigned* __restrict__ cand, unsigned cap, int n4, int n) {
  __shared__ unsigned lbuf[K3_MAX_LOCAL];
  __shared__ unsigned lcnt;
  __shared__ unsigned gbase;
  __shared__ double sws[4];
  if (threadIdx.x == 0) { lcnt = 0u; gbase = 0u; }
  __syncthreads();

  const int B = ctrl->B;
  double ssum = 0.0;
  const float4* p4 = (const float4*)pred;
  const float4* g4 = (const float4*)gt;
  const float4* m4 = (const float4*)mask;
  int gtid = blockIdx.x * blockDim.x + threadIdx.x;
  int stride = gridDim.x * blockDim.x;

  for (int i = gtid; i < n4; i += stride) {
    float4 pv = p4[i], gv = g4[i], mv = m4[i];
    float pa[4] = {pv.x, pv.y, pv.z, pv.w};
    float ga[4] = {gv.x, gv.y, gv.z, gv.w};
    float ma[4] = {mv.x, mv.y, mv.z, mv.w};
#pragma unroll
    for (int j = 0; j < 4; j++) {
      if (ma[j] != 0.0f && ga[j] == 0.0f) {
        float loss = neg_loss_from(pa[j]);
        unsigned bits = __float_as_uint(loss);
        int b = (int)(bits >> 19);
        if (b > B) ssum += (double)loss;
        else if (b == B) {
          unsigned idx = atomicAdd(&lcnt, 1u);
          if (idx < K3_MAX_LOCAL) lbuf[idx] = bits;
        }
      }
    }
  }
  for (int i = n4 * 4 + gtid; i < n; i += stride) {
    float p = pred[i], g = gt[i], m = mask[i];
    if (m != 0.0f && g == 0.0f) {
      float loss = neg_loss_from(p);
      unsigned bits = __float_as_uint(loss);
      int b = (int)(bits >> 19);
      if (b > B) ssum += (double)loss;
      else if (b == B) {
        unsigned idx = atomicAdd(&lcnt, 1u);
        if (idx < K3_MAX_LOCAL) lbuf[idx] = bits;
      }
    }
  }

  for (int off = 32; off > 0; off >>= 1) ssum += __shfl_down(ssum, off);
  int wv = threadIdx.x >> 6, ln = threadIdx.x & 63;
  if (ln == 0) sws[wv] = ssum;
  __syncthreads();   // all appends + wave sums complete
  if (threadIdx.x == 0) {
    double tsum = sws[0] + sws[1] + sws[2] + sws[3];
    atomicAdd(&ctrl->sum_above, tsum);
    unsigned c = lcnt;
    if (c > K3_MAX_LOCAL) c = K3_MAX_LOCAL;
    lcnt = c;
    gbase = c ? atomicAdd(&ctrl->cand_cnt, c) : 0u;
  }
  __syncthreads();
  unsigned c = lcnt, base = gbase;
  for (unsigned i = threadIdx.x; i < c; i += blockDim.x) {
    unsigned dst = base + i;
    if (dst < cap) cand[dst] = lbuf[i];
  }
}

// ------- Kernel 4: levels 2+3 on candidates, final result (1 block) --------
extern "C" __global__ void __launch_bounds__(1024)
k4_final(const unsigned* __restrict__ cand, Ctrl* __restrict__ ctrl,
         float* __restrict__ out, unsigned cap) {
  const int T = 1024, CH2 = NBINS2 / T;  // 4 bins per thread
  __shared__ unsigned h2[NBINS2];
  __shared__ unsigned h3[NBINS3];
  __shared__ unsigned long long sarr[T];
  __shared__ int sB2;
  __shared__ unsigned sk2;
  __shared__ double sws[16];
  int t = threadIdx.x;

  unsigned M = ctrl->cand_cnt; if (M > cap) M = cap;
  unsigned k_rem = ctrl->k_rem;

  for (int i = t; i < NBINS2; i += T) h2[i] = 0u;
  for (int i = t; i < NBINS3; i += T) h3[i] = 0u;
  if (t == 0) { sB2 = NBINS2; sk2 = 0u; }
  __syncthreads();

  if (k_rem > 0) {
    for (unsigned i = t; i < M; i += T)
      atomicAdd(&h2[(cand[i] >> 7) & 0xFFFu], 1u);
  }
  __syncthreads();

  // suffix scan over 4-bin chunks of h2
  unsigned cnt2[CH2];
  unsigned long long tot = 0;
  for (int j = 0; j < CH2; j++) { cnt2[j] = h2[t * CH2 + j]; tot += cnt2[j]; }
  sarr[t] = tot;
  __syncthreads();
  for (int off = 1; off < T; off <<= 1) {
    unsigned long long v = (t + off < T) ? sarr[t + off] : 0ull;
    __syncthreads();
    sarr[t] += v;
    __syncthreads();
  }
  if (k_rem > 0) {
    unsigned long long above = sarr[t] - tot;
    if (above < (unsigned long long)k_rem &&
        sarr[t] >= (unsigned long long)k_rem) {
      unsigned long long cum = above;
      for (int j = CH2 - 1; j >= 0; j--) {
        if (cum + (unsigned long long)cnt2[j] >= (unsigned long long)k_rem) {
          sB2 = t * CH2 + j;
          sk2 = (unsigned)((unsigned long long)k_rem - cum);
          break;
        }
        cum += cnt2[j];
      }
    }
  }
  __syncthreads();
  int B2 = sB2; unsigned k2r = sk2;

  // sum values strictly above sub-bin B2; exact-value histogram inside B2
  double ssum = 0.0;
  if (k_rem > 0) {
    for (unsigned i = t; i < M; i += T) {
      unsigned bits = cand[i];
      int b2 = (int)((bits >> 7) & 0xFFFu);
      if (b2 > B2) ssum += (double)__uint_as_float(bits);
      else if (b2 == B2) atomicAdd(&h3[bits & 0x7Fu], 1u);
    }
  }
  for (int off = 32; off > 0; off >>= 1) ssum += __shfl_down(ssum, off);
  int wv = t >> 6, ln = t & 63;
  if (ln == 0) sws[wv] = ssum;
  __syncthreads();

  if (t == 0) {
    double sum2 = 0.0;
    for (int w = 0; w < T / 64; w++) sum2 += sws[w];
    double partial = 0.0;
    unsigned rem = k2r;
    unsigned base = ((unsigned)ctrl->B << 19) | ((unsigned)B2 << 7);
    for (int b = NBINS3 - 1; b >= 0 && rem > 0; b--) {
      unsigned c = h3[b];
      if (!c) continue;
      unsigned take = (c < rem) ? c : rem;
      // all 32 bits fixed here => ties share one exact value
      partial += (double)take * (double)__uint_as_float(base | (unsigned)b);
      rem -= take;
    }
    double neg_sum = ctrl->sum_above + sum2 + partial;
    double denom = (double)ctrl->pos_cnt + (double)ctrl->k + 1e-6;
    out[0] = (float)((ctrl->pos_sum + neg_sum) / denom);
  }
}

// ---------------------------------------------------------------------------
extern "C" void kernel_launch(void* const* d_in, const int* in_sizes, int n_in,
                              void* d_out, int out_size, void* d_ws, size_t ws_size,
                              hipStream_t stream) {
  const float* pred = (const float*)d_in[0];
  const float* gt   = (const float*)d_in[1];
  const float* mask = (const float*)d_in[2];
  float* out = (float*)d_out;
  int n = in_sizes[0];
  int n4 = n / 4;

  char* ws = (char*)d_ws;
  Ctrl* ctrl = (Ctrl*)ws;
  unsigned* hist1 = (unsigned*)(ws + 256);
  size_t cand_off = 256 + (size_t)NBINS1 * sizeof(unsigned);
  unsigned* cand = (unsigned*)(ws + cand_off);
  unsigned cap = 0;
  if (ws_size > cand_off + 4) {
    size_t c = (ws_size - cand_off) / 4;
    cap = (c > (size_t)n) ? (unsigned)n : (unsigned)c;
  }

  hipMemsetAsync(d_ws, 0, cand_off, stream);
  k1_hist<<<K1_BLOCKS, 256, 0, stream>>>(pred, gt, mask, hist1, ctrl, n4, n);
  k2_select<<<1, 256, 0, stream>>>(hist1, ctrl);
  int blocks3 = (n4 + K3_VEC_PER_BLOCK - 1) / K3_VEC_PER_BLOCK;
  if (blocks3 < 1) blocks3 = 1;
  k3_compact<<<blocks3, 256, 0, stream>>>(pred, gt, mask, ctrl, cand, cap, n4, n);
  k4_final<<<1, 1024, 0, stream>>>(cand, ctrl, out, cap);
}